// Round 4
// baseline (143.275 us; speedup 1.0000x reference)
//
#include <hip/hip_runtime.h>
#include <cstddef>

namespace {
constexpr int cB = 64, cN = 34, cF = 16, cT = 96, cK = 3, cO = 64;
constexpr int TT = 4;     // t-tile per block
constexpr int LP = 68;    // bf16 col pitch for 48/34-row matrices (136B rows -> 2-way-free banks)
constexpr int HP = 104;   // s_H pitch (bf16), proven in rounds 2-3
constexpr float cEPS = 1e-8f;

typedef __attribute__((ext_vector_type(8))) short bf16x8;
typedef __attribute__((ext_vector_type(4))) float f32x4;

__device__ inline short f2bf(float v) {  // round-to-nearest-even f32 -> bf16 bits
    union { float f; unsigned u; } x; x.f = v;
    unsigned r = x.u + 0x7fffu + ((x.u >> 16) & 1u);
    return (short)(r >> 16);
}
__device__ inline float bf2f(unsigned short u) {
    union { unsigned u; float f; } x; x.u = ((unsigned)u) << 16; return x.f;
}
}

// ---------------- softmax over axis=2 (i) of st_attention (B,K,N,N) ----------------
__global__ __launch_bounds__(256) void att_softmax_k(const float* __restrict__ st,
                                                     float* __restrict__ att) {
    int idx = blockIdx.x * blockDim.x + threadIdx.x;
    if (idx >= cB * cK * cN) return;
    int j = idx % cN;
    int bk = idx / cN;
    const float* base = st + (size_t)bk * cN * cN + j;
    float v[cN];
    float m = -3.402823466e38f;
#pragma unroll
    for (int i = 0; i < cN; ++i) { v[i] = base[(size_t)i * cN]; m = fmaxf(m, v[i]); }
    float s = 0.f;
#pragma unroll
    for (int i = 0; i < cN; ++i) { v[i] = __expf(v[i] - m); s += v[i]; }
    float inv = 1.f / s;
    float* ob = att + (size_t)bk * cN * cN + j;
#pragma unroll
    for (int i = 0; i < cN; ++i) ob[(size_t)i * cN] = v[i] * inv;
}

// ---------------- main: one block per (b, 4-t tile); all matmuls on MFMA ----------------
__global__ __launch_bounds__(256, 2) void cheb_main_k(
    const float* __restrict__ x,      // (B,N,F,T)
    const float* __restrict__ att,    // (B,K,N,N) softmaxed
    const float* __restrict__ pos,    // (N,2)
    const float* __restrict__ dist,   // (N,N)
    const float* __restrict__ Th,     // (K,F,O)
    const float* __restrict__ ThL,    // (K,F,O)
    float* __restrict__ out)          // (B,N,O,T)
{
    // bf16 matrices, [48 rows][LP cols]; rows/cols >=34 stay zero (k-padding)
    __shared__ __align__(16) unsigned short s_L1hi[48 * LP]; // A(fp32) overlays rows 0..33 each tt
    __shared__ __align__(16) unsigned short s_L1lo[48 * LP]; // -> M2T after C-phase
    __shared__ __align__(16) unsigned short s_L2hi[48 * LP];
    __shared__ __align__(16) unsigned short s_L2lo[48 * LP]; // -> M4T
    __shared__ __align__(16) unsigned short s_M1T[48 * LP];
    __shared__ __align__(16) unsigned short s_M3T[48 * LP];
    __shared__ __align__(16) unsigned short s_gsT[16 * LP];  // gs^T bf16 (B-op of H)
    __shared__ __align__(16) unsigned short s_H[144 * HP];   // stacked H, row = 4*j + tt
    __shared__ unsigned short s_at1[cN * cN], s_at2[cN * cN];
    __shared__ float s_d0[cN], s_v1[cN], s_v2[cN], s_p1[cN], s_p2[cN], s_di1[cN], s_di2[cN];

    const int tid = threadIdx.x;
    const int lane = tid & 63;
    const int w = tid >> 6;
    const int lr = lane & 15;    // tile row/col index
    const int lg = lane >> 4;    // k-group
    const int kb8 = lg * 8;
    const int ocol = w * 16 + lr;

    // XCD swizzle (grid 1536, %8==0 -> bijective)
    const unsigned g = blockIdx.x;
    const unsigned lin = (g & 7u) * (cB * (cT / TT) / 8) + (g >> 3);
    const int b = lin / (cT / TT);
    const int t0 = (lin % (cT / TT)) * TT;

    // ---- Theta B-fragments (c = p*16+f; p0 = Th0+ThL0 merged), as round 3 ----
    bf16x8 bfr[3];
#pragma unroll
    for (int s = 0; s < 3; ++s) {
#pragma unroll
        for (int j = 0; j < 8; ++j) {
            int cc = 32 * s + kb8 + j;
            float v = 0.f;
            if (cc < 80) {
                int p = cc >> 4, f = cc & 15;
                if (p == 0)      v = Th[f * cO + ocol] + ThL[f * cO + ocol];
                else if (p == 1) v = Th[(cF + f) * cO + ocol];
                else if (p == 2) v = Th[(2 * cF + f) * cO + ocol];
                else if (p == 3) v = ThL[(cF + f) * cO + ocol];
                else             v = ThL[(2 * cF + f) * cO + ocol];
            }
            bfr[s][j] = f2bf(v);
        }
    }

    // ---- block init: zero bf16 arrays (pads must be 0), stage att/d0/p-hat ----
    {
        float4 z = make_float4(0.f, 0.f, 0.f, 0.f);
        for (int i2 = tid; i2 < 48 * LP / 8; i2 += 256) {
            ((float4*)s_L1hi)[i2] = z; ((float4*)s_L1lo)[i2] = z;
            ((float4*)s_L2hi)[i2] = z; ((float4*)s_L2lo)[i2] = z;
            ((float4*)s_M1T)[i2] = z;  ((float4*)s_M3T)[i2] = z;
        }
        for (int i2 = tid; i2 < 16 * LP / 8; i2 += 256) ((float4*)s_gsT)[i2] = z;
        for (int i2 = tid; i2 < 144 * HP / 8; i2 += 256) ((float4*)s_H)[i2] = z;
        const float* a1g = att + ((size_t)b * cK + 1) * cN * cN;
        const float* a2g = att + ((size_t)b * cK + 2) * cN * cN;
        for (int idx = tid; idx < cN * cN; idx += 256) {
            s_at1[idx] = (unsigned short)f2bf(a1g[idx]);
            s_at2[idx] = (unsigned short)f2bf(a2g[idx]);
        }
        if (tid < cN) {
            float px = pos[2 * tid], py = pos[2 * tid + 1];
            float pn = sqrtf(px * px + py * py);
            float r = 1.f / fmaxf(pn, cEPS);
            s_p1[tid] = px * r; s_p2[tid] = py * r;
            s_d0[tid] = att[((size_t)b * cK) * cN * cN + tid * cN + tid];
        }
    }
    __syncthreads();

    for (int tt = 0; tt < TT; ++tt) {
        const int t = t0 + tt;

        // ---- P1: per-t staging: v' (vn-folded), gsT bf16 ----
        if (tid < cN) {
            float x1 = x[(((size_t)b * cN + tid) * cF + 1) * cT + t];
            float x2 = x[(((size_t)b * cN + tid) * cF + 2) * cT + t];
            float vn = sqrtf(x1 * x1 + x2 * x2);
            float s = vn / fmaxf(vn, cEPS);
            s_v1[tid] = x1 * s; s_v2[tid] = x2 * s;
        }
        for (int idx = tid; idx < cN * cF; idx += 256) {
            int n = idx >> 4, f = idx & 15;
            s_gsT[f * LP + n] = (unsigned short)f2bf(x[(((size_t)b * cN + n) * cF + f) * cT + t]);
        }
        __syncthreads();

        // ---- P2: adjacency A (fp32) into L1hi region (Frobenius norm skipped) ----
        float* Af = (float*)s_L1hi;
#pragma unroll
        for (int e = 0; e < 5; ++e) {
            int idx = tid + 256 * e;
            if (idx < cN * cN) {
                int i = idx / cN, m = idx - i * cN;
                float dot = s_v1[i] * s_p1[m] + s_v2[i] * s_p2[m];
                Af[idx] = __fdividef(fmaxf(dot, 0.f), dist[idx]);
            }
        }
        __syncthreads();

        // ---- P2b: degrees; P3a: read A pairs into regs (before L overwrites A) ----
        if (tid < cN) {
            float s = 0.f;
#pragma unroll
            for (int m = 0; m < cN; ++m) s += Af[tid * cN + m];
            s_di1[tid] = (s > 0.f) ? rsqrtf(fmaxf(s, 1e-12f)) : 0.f;
        } else if (tid >= 64 && tid < 64 + cN) {
            int j = tid - 64;
            float s = 0.f;
#pragma unroll
            for (int i = 0; i < cN; ++i) s += Af[i * cN + j];
            s_di2[j] = (s > 0.f) ? rsqrtf(fmaxf(s, 1e-12f)) : 0.f;
        }
        float aij[5], aji[5];
#pragma unroll
        for (int e = 0; e < 5; ++e) {
            int idx = tid + 256 * e;
            if (idx < cN * cN) {
                int i = idx / cN, j = idx - i * cN;
                aij[e] = Af[idx];
                aji[e] = Af[j * cN + i];
            }
        }
        __syncthreads();

        // ---- P3b: L1 = I - d1 A d1 (hi/lo bf16), L2 = I - d2 A^T d2; M1T/M3T; re-zero pads ----
#pragma unroll
        for (int e = 0; e < 5; ++e) {
            int idx = tid + 256 * e;
            if (idx < cN * cN) {
                int i = idx / cN, j = idx - i * cN;
                float diag = (i == j) ? 1.f : 0.f;
                float l1 = diag - s_di1[i] * aij[e] * s_di1[j];
                float l2 = diag - s_di2[i] * aji[e] * s_di2[j];
                short h1 = f2bf(l1); float lo1 = l1 - bf2f((unsigned short)h1);
                short h2 = f2bf(l2); float lo2 = l2 - bf2f((unsigned short)h2);
                int rm = i * LP + j;
                s_L1hi[rm] = (unsigned short)h1; s_L1lo[rm] = (unsigned short)f2bf(lo1);
                s_L2hi[rm] = (unsigned short)h2; s_L2lo[rm] = (unsigned short)f2bf(lo2);
                s_L1hi[rm + cN] = 0;  // re-zero pad col dirtied by the fp32-A overlay
                float a1 = bf2f(s_at1[idx]);
                int tm = j * LP + i;
                s_M1T[tm] = (unsigned short)f2bf(a1 * l1);
                s_M3T[tm] = (unsigned short)f2bf(a1 * l2);
            }
        }
        __syncthreads();

        // ---- P4: C = L@L via split-bf16 MFMA; wave: mat = w>>1, nts = (w&1)?{2}:{0,1} ----
        const unsigned short* Ah = (w < 2) ? s_L1hi : s_L2hi;
        const unsigned short* Al = (w < 2) ? s_L1lo : s_L2lo;
        const int nnt = (w & 1) ? 1 : 2;
        const int ntb0 = (w & 1) ? 32 : 0;
        f32x4 cd0[3], cd1[3];
#pragma unroll
        for (int mt = 0; mt < 3; ++mt) {
            cd0[mt] = (f32x4){0.f, 0.f, 0.f, 0.f};
            cd1[mt] = (f32x4){0.f, 0.f, 0.f, 0.f};
        }
#pragma unroll
        for (int ks = 0; ks < 2; ++ks) {
            bf16x8 fah[3], fal[3];
#pragma unroll
            for (int mt = 0; mt < 3; ++mt) {
                int ro = (mt * 16 + lr) * LP + 32 * ks + kb8;
                fah[mt] = *(const bf16x8*)&Ah[ro];
                fal[mt] = *(const bf16x8*)&Al[ro];
            }
#pragma unroll
            for (int un = 0; un < 2; ++un) {
                if (un == 1 && nnt < 2) break;
                int col = ntb0 + un * 16 + lr;
                bf16x8 fbh, fbl;
#pragma unroll
                for (int e2 = 0; e2 < 8; ++e2) {
                    int kk = 32 * ks + kb8 + e2;
                    bool vld = kk < 48;
                    fbh[e2] = vld ? (short)Ah[kk * LP + col] : (short)0;
                    fbl[e2] = vld ? (short)Al[kk * LP + col] : (short)0;
                }
#pragma unroll
                for (int mt = 0; mt < 3; ++mt) {
                    f32x4 acc = un ? cd1[mt] : cd0[mt];
                    acc = __builtin_amdgcn_mfma_f32_16x16x32_bf16(fah[mt], fbh, acc, 0, 0, 0);
                    acc = __builtin_amdgcn_mfma_f32_16x16x32_bf16(fal[mt], fbh, acc, 0, 0, 0);
                    acc = __builtin_amdgcn_mfma_f32_16x16x32_bf16(fah[mt], fbl, acc, 0, 0, 0);
                    if (un) cd1[mt] = acc; else cd0[mt] = acc;
                }
            }
        }
        __syncthreads();  // all L reads done before M2T/M4T overlay writes

        // ---- P5: M2T = att2 .* (2C1 - I) into L1lo; M4T same into L2lo ----
        {
            unsigned short* Md = (w < 2) ? s_L1lo : s_L2lo;
#pragma unroll
            for (int un = 0; un < 2; ++un) {
                if (un == 1 && nnt < 2) break;
                int jb = ntb0 + un * 16 + lr;  // C col = j index
                if (jb < cN) {
#pragma unroll
                    for (int mt = 0; mt < 3; ++mt) {
#pragma unroll
                        for (int r = 0; r < 4; ++r) {
                            int i = mt * 16 + lg * 4 + r;
                            if (i < cN) {
                                float dv = un ? cd1[mt][r] : cd0[mt][r];
                                float a2 = bf2f(s_at2[i * cN + jb]);
                                float cv = 2.f * dv - ((i == jb) ? 1.f : 0.f);
                                Md[jb * LP + i] = (unsigned short)f2bf(a2 * cv);
                            }
                        }
                    }
                }
            }
        }
        __syncthreads();

        // ---- P6: H_p = M_p^T @ gs via MFMA (wave w -> p = w+1), + p0 diag block ----
        {
            const unsigned short* Ap = (w == 0) ? s_M1T : (w == 1) ? s_L1lo
                                     : (w == 2) ? s_M3T : s_L2lo;
            f32x4 hd[3];
#pragma unroll
            for (int mt = 0; mt < 3; ++mt) hd[mt] = (f32x4){0.f, 0.f, 0.f, 0.f};
#pragma unroll
            for (int ks = 0; ks < 2; ++ks) {
                bf16x8 fb = *(const bf16x8*)&s_gsT[lr * LP + 32 * ks + kb8];
#pragma unroll
                for (int mt = 0; mt < 3; ++mt) {
                    bf16x8 fa = *(const bf16x8*)&Ap[(mt * 16 + lr) * LP + 32 * ks + kb8];
                    hd[mt] = __builtin_amdgcn_mfma_f32_16x16x32_bf16(fa, fb, hd[mt], 0, 0, 0);
                }
            }
            int pc = 16 * (w + 1);
#pragma unroll
            for (int mt = 0; mt < 3; ++mt) {
#pragma unroll
                for (int r = 0; r < 4; ++r) {
                    int j = mt * 16 + lg * 4 + r;
                    if (j < cN)
                        s_H[(4 * j + tt) * HP + pc + lr] = (unsigned short)f2bf(hd[mt][r]);
                }
            }
            int j0 = w * 9;
            int jn = (j0 + 9 <= cN) ? 9 : (cN - j0);
            for (int idx = lane; idx < jn * 16; idx += 64) {
                int j = j0 + (idx >> 4), f = idx & 15;
                s_H[(4 * j + tt) * HP + f] =
                    (unsigned short)f2bf(s_d0[j] * bf2f(s_gsT[f * LP + j]));
            }
        }
        __syncthreads();
    }

    // ---- P7: out = relu(H @ Thcat); stacked rows give float4-over-t stores ----
    f32x4 acc[9];
#pragma unroll
    for (int mt = 0; mt < 9; ++mt) acc[mt] = (f32x4){0.f, 0.f, 0.f, 0.f};
#pragma unroll
    for (int s = 0; s < 3; ++s) {
#pragma unroll
        for (int mt = 0; mt < 9; ++mt) {
            bf16x8 a = *(const bf16x8*)&s_H[(mt * 16 + lr) * HP + kb8 + 32 * s];
            acc[mt] = __builtin_amdgcn_mfma_f32_16x16x32_bf16(a, bfr[s], acc[mt], 0, 0, 0);
        }
    }
#pragma unroll
    for (int mt = 0; mt < 9; ++mt) {
        int j = 4 * mt + lg;
        if (j < cN) {
            float4 v;
            v.x = fmaxf(acc[mt][0], 0.f);
            v.y = fmaxf(acc[mt][1], 0.f);
            v.z = fmaxf(acc[mt][2], 0.f);
            v.w = fmaxf(acc[mt][3], 0.f);
            *(float4*)&out[(((size_t)b * cN + j) * cO + ocol) * cT + t0] = v;
        }
    }
}

extern "C" void kernel_launch(void* const* d_in, const int* in_sizes, int n_in,
                              void* d_out, int out_size, void* d_ws, size_t ws_size,
                              hipStream_t stream) {
    const float* x    = (const float*)d_in[0];
    const float* st   = (const float*)d_in[1];
    const float* pos  = (const float*)d_in[2];
    const float* dist = (const float*)d_in[3];
    const float* Th   = (const float*)d_in[4];
    const float* ThL  = (const float*)d_in[5];
    float* out = (float*)d_out;
    float* att = (float*)d_ws;  // B*K*N*N floats = 888 KB

    att_softmax_k<<<(cB * cK * cN + 255) / 256, 256, 0, stream>>>(st, att);
    cheb_main_k<<<cB * (cT / TT), 256, 0, stream>>>(x, att, pos, dist, Th, ThL, out);
}